// Round 1
// baseline (232.232 us; speedup 1.0000x reference)
//
#include <hip/hip_runtime.h>

#define BM    128
#define NC    64
#define KDIM  128
#define NCODES 1024
#define FSTR  136      // fLds/eLds row stride in bf16 elements (pad 128->136, kills 16-way conflicts)
#define SSTR  68       // score LDS row stride in floats (pad 64->68, float4-aligned, <=2-way)
#define NELEM 8388608  // 8192 * 1024

typedef __attribute__((ext_vector_type(8))) short  short8;
typedef __attribute__((ext_vector_type(8))) __bf16 bf16x8;
typedef __attribute__((ext_vector_type(4))) float  f32x4;

__device__ inline ushort f2bf(float f) {            // round-to-nearest-even fp32 -> bf16
  unsigned u = __builtin_bit_cast(unsigned, f);
  u += 0x7fffu + ((u >> 16) & 1u);
  return (ushort)(u >> 16);
}
__device__ inline float bf2f(ushort b) {
  unsigned u = ((unsigned)b) << 16;
  return __builtin_bit_cast(float, u);
}
__device__ inline unsigned ordf(float f) {          // monotone float -> uint map
  unsigned u = __builtin_bit_cast(unsigned, f);
  u ^= (unsigned)(((int)u >> 31)) | 0x80000000u;
  return u;
}
__device__ inline f32x4 mfma_bf16(short8 a, short8 b, f32x4 c) {
  return __builtin_amdgcn_mfma_f32_16x16x32_bf16(
      __builtin_bit_cast(bf16x8, a), __builtin_bit_cast(bf16x8, b), c, 0, 0, 0);
}
__device__ inline void ins8(unsigned long long key, unsigned long long (&top)[8]) {
  if (key < top[7]) {
#pragma unroll
    for (int p = 0; p < 8; ++p) {
      unsigned long long lo = key < top[p] ? key : top[p];
      unsigned long long hi = key < top[p] ? top[p] : key;
      top[p] = lo;
      key = hi;
    }
  }
}

// ---- prep: embedding fp32 -> bf16 copy + per-code squared norms ----
__global__ void vq_prep(const float* __restrict__ emb, ushort* __restrict__ ebf,
                        float* __restrict__ esq) {
  int j = blockIdx.x, d = threadIdx.x;       // 1024 blocks x 128 threads
  float v = emb[j * KDIM + d];
  ebf[j * KDIM + d] = f2bf(v);
  float s = v * v;
#pragma unroll
  for (int off = 32; off; off >>= 1) s += __shfl_down(s, off);
  __shared__ float w[2];
  if ((threadIdx.x & 63) == 0) w[threadIdx.x >> 6] = s;
  __syncthreads();
  if (threadIdx.x == 0) esq[j] = w[0] + w[1];
}

// ---- main: fused dist-GEMM + top8 select + gather + loss partial ----
__global__ __launch_bounds__(256, 2) void vq_main(
    const float* __restrict__ lat, const float* __restrict__ emb,
    const int* __restrict__ ksel, const ushort* __restrict__ ebf,
    const float* __restrict__ esq, float* __restrict__ out,
    float* __restrict__ partial) {
  __shared__ __align__(16) ushort fLds[BM * FSTR];            // 34816 B
  __shared__ __align__(16) unsigned char uni[BM * SSTR * 4];  // 34816 B (eTile | scores | merge)
  __shared__ int selLds[BM];
  __shared__ float redLds[4];

  ushort* eLds = (ushort*)uni;
  float* sLds = (float*)uni;
  unsigned long long* mbuf = (unsigned long long*)uni;

  const int tid = threadIdx.x;
  const int lane = tid & 63, wid = tid >> 6;
  const int gR0 = blockIdx.x * BM;

  // stage latents tile: 128 rows x 128 k, fp32 -> bf16
  for (int i = tid; i < BM * (KDIM / 4); i += 256) {
    int row = i >> 5, c4 = i & 31;
    const float4 v = *(const float4*)(lat + (size_t)(gR0 + row) * KDIM + c4 * 4);
    ushort4 b;
    b.x = f2bf(v.x); b.y = f2bf(v.y); b.z = f2bf(v.z); b.w = f2bf(v.w);
    *(ushort4*)(&fLds[row * FSTR + c4 * 4]) = b;
  }

  unsigned long long top[8];
#pragma unroll
  for (int p = 0; p < 8; ++p) top[p] = ~0ULL;

  const int scanRow = tid >> 1, scanHalf = tid & 1;
  const int lc = lane & 15, kOff = (lane >> 4) * 8;

  __syncthreads();

  for (int n0 = 0; n0 < NCODES; n0 += NC) {
    // stage 64-code bf16 tile
    for (int i = tid; i < NC * (KDIM / 8); i += 256) {
      int row = i >> 4, c8 = i & 15;
      short8 v = *(const short8*)(ebf + (size_t)(n0 + row) * KDIM + c8 * 8);
      *(short8*)(&eLds[row * FSTR + c8 * 8]) = v;
    }
    __syncthreads();

    f32x4 acc[2][4];
#pragma unroll
    for (int rt = 0; rt < 2; ++rt)
#pragma unroll
      for (int ct = 0; ct < 4; ++ct) acc[rt][ct] = (f32x4){0.f, 0.f, 0.f, 0.f};

#pragma unroll
    for (int ks = 0; ks < 4; ++ks) {
      const int k0 = ks * 32;
      short8 af[2];
#pragma unroll
      for (int rt = 0; rt < 2; ++rt)
        af[rt] = *(const short8*)(&fLds[(wid * 32 + rt * 16 + lc) * FSTR + k0 + kOff]);
#pragma unroll
      for (int ct = 0; ct < 4; ++ct) {
        short8 bfr = *(const short8*)(&eLds[(ct * 16 + lc) * FSTR + k0 + kOff]);
#pragma unroll
        for (int rt = 0; rt < 2; ++rt) acc[rt][ct] = mfma_bf16(af[rt], bfr, acc[rt][ct]);
      }
    }
    __syncthreads();  // all eLds reads done before overlaying scores

    // score = ||e||^2 - 2 * dot  -> sLds[row][col]
#pragma unroll
    for (int ct = 0; ct < 4; ++ct) {
      const int col = ct * 16 + lc;
      const float eq = esq[n0 + col];
#pragma unroll
      for (int rt = 0; rt < 2; ++rt) {
        const int row0 = wid * 32 + rt * 16 + (lane >> 4) * 4;
#pragma unroll
        for (int r = 0; r < 4; ++r)
          sLds[(row0 + r) * SSTR + col] = eq - 2.0f * acc[rt][ct][r];
      }
    }
    __syncthreads();

    // per-thread scan of 32 scores (half a row-chunk), maintain sorted top-8
    const float4* sp = (const float4*)(sLds + scanRow * SSTR + scanHalf * 32);
#pragma unroll
    for (int j = 0; j < 8; ++j) {
      float4 v = sp[j];
      const int cb = n0 + scanHalf * 32 + j * 4;
      ins8(((unsigned long long)ordf(v.x) << 32) | (unsigned)(cb + 0), top);
      ins8(((unsigned long long)ordf(v.y) << 32) | (unsigned)(cb + 1), top);
      ins8(((unsigned long long)ordf(v.z) << 32) | (unsigned)(cb + 2), top);
      ins8(((unsigned long long)ordf(v.w) << 32) | (unsigned)(cb + 3), top);
    }
    __syncthreads();
  }

  // dump both half-row top8 lists, merge, pick k[c]-th
#pragma unroll
  for (int p = 0; p < 8; ++p) mbuf[(unsigned)tid * 8u + p] = top[p];
  __syncthreads();
  if (tid < BM) {
    const unsigned long long* A = &mbuf[(unsigned)(tid * 2 + 0) * 8u];
    const unsigned long long* B = &mbuf[(unsigned)(tid * 2 + 1) * 8u];
    const int c = (gR0 + tid) & 7;
    int kk = ksel[c];
    kk = kk < 0 ? 0 : (kk > 7 ? 7 : kk);
    int i = 0, j = 0;
    unsigned long long sel = 0;
    for (int s = 0; s <= kk; ++s) {
      unsigned long long a = A[i], b = B[j];
      if (a < b) { sel = a; ++i; } else { sel = b; ++j; }
    }
    selLds[tid] = (int)(unsigned)(sel & 0xFFFFFFFFu);
  }
  __syncthreads();

  // epilogue: gather selected code rows (fp32), write out, accumulate loss
  float ls = 0.f;
  for (int i = tid; i < BM * (KDIM / 4); i += 256) {
    int row = i >> 5, c4 = i & 31;
    int sel = selLds[row];
    float4 q = *(const float4*)(emb + (size_t)sel * KDIM + c4 * 4);
    ushort4 lb = *(const ushort4*)(&fLds[row * FSTR + c4 * 4]);
    float d0 = q.x - bf2f(lb.x), d1 = q.y - bf2f(lb.y);
    float d2 = q.z - bf2f(lb.z), d3 = q.w - bf2f(lb.w);
    ls += d0 * d0 + d1 * d1 + d2 * d2 + d3 * d3;
    *(float4*)(out + (size_t)(gR0 + row) * KDIM + c4 * 4) = q;
  }
#pragma unroll
  for (int off = 32; off; off >>= 1) ls += __shfl_down(ls, off);
  if (lane == 0) redLds[wid] = ls;
  __syncthreads();
  if (tid == 0) partial[blockIdx.x] = redLds[0] + redLds[1] + redLds[2] + redLds[3];
}

// ---- deterministic loss reduction over 512 block partials ----
__global__ void vq_reduce(const float* __restrict__ partial, float* __restrict__ loss) {
  __shared__ float w[4];
  int t = threadIdx.x;
  float s = partial[t] + partial[t + 256];
#pragma unroll
  for (int off = 32; off; off >>= 1) s += __shfl_down(s, off);
  if ((t & 63) == 0) w[t >> 6] = s;
  __syncthreads();
  if (t == 0) loss[0] = (w[0] + w[1] + w[2] + w[3]) * (1.25f / (float)NELEM);
}

extern "C" void kernel_launch(void* const* d_in, const int* in_sizes, int n_in,
                              void* d_out, int out_size, void* d_ws, size_t ws_size,
                              hipStream_t stream) {
  const float* lat = (const float*)d_in[0];   // [8192, 1024] fp32
  const float* emb = (const float*)d_in[1];   // [1024, 128]  fp32
  const int* ksel = (const int*)d_in[2];      // [8] int32
  float* out = (float*)d_out;                 // [8388608] quantized + [1] loss

  ushort* ebf = (ushort*)d_ws;                          // 262144 B
  float* esq = (float*)((char*)d_ws + 262144);          // 4096 B
  float* partial = (float*)((char*)d_ws + 262144 + 4096);  // 2048 B

  vq_prep<<<1024, 128, 0, stream>>>(emb, ebf, esq);
  vq_main<<<512, 256, 0, stream>>>(lat, emb, ksel, ebf, esq, out, partial);
  vq_reduce<<<1, 256, 0, stream>>>(partial, out + NELEM);
}

// Round 2
// 170.815 us; speedup vs baseline: 1.3596x; 1.3596x over previous
//
#include <hip/hip_runtime.h>

#define KDIM   128
#define BM     64
#define NELEM  8388608

// LDS layout (bytes): [0,17408) fLds ushort[64][136] (ebuf1 aliases first 16384)
// [17408,33792) ebuf0 / merge buffer; [33792,37888) esqLds f32[1024];
// [37888,38144) fsqLds f32[64]; [38144,38400) selLds i32[64]
#define OFF_EBUF0 17408
#define OFF_ESQ   33792
#define OFF_FSQ   37888
#define OFF_SEL   38144
#define SMEM_SZ   38400

typedef __attribute__((ext_vector_type(8)))  short  short8;
typedef __attribute__((ext_vector_type(8)))  __bf16 bf16x8;
typedef __attribute__((ext_vector_type(4)))  float  f32x4;
typedef unsigned long long u64;

__device__ inline ushort f2bf(float f) {            // RNE fp32 -> bf16
  unsigned u = __builtin_bit_cast(unsigned, f);
  u += 0x7fffu + ((u >> 16) & 1u);
  return (ushort)(u >> 16);
}
__device__ inline unsigned ordf(float f) {          // monotone float -> uint
  unsigned u = __builtin_bit_cast(unsigned, f);
  return u ^ ((unsigned)((int)u >> 31) | 0x80000000u);
}
__device__ inline float inv_ordf(unsigned y) {
  unsigned m = (unsigned)((int)(~y) >> 31) | 0x80000000u;
  return __builtin_bit_cast(float, y ^ m);
}
__device__ inline f32x4 mfma16(short8 a, short8 b, f32x4 c) {
  return __builtin_amdgcn_mfma_f32_16x16x32_bf16(
      __builtin_bit_cast(bf16x8, a), __builtin_bit_cast(bf16x8, b), c, 0, 0, 0);
}
__device__ inline void gload16(const void* g, void* l) {
  __builtin_amdgcn_global_load_lds(
      (const __attribute__((address_space(1))) unsigned*)g,
      (__attribute__((address_space(3))) unsigned*)l, 16, 0, 0);
}
__device__ inline void cand(float sc, int code, u64 (&top)[8], float& top7f) {
  if (sc < top7f) {                                 // ties skipped => stable (codes ascend)
    u64 key = ((u64)ordf(sc) << 32) | (unsigned)code;
#pragma unroll
    for (int p = 0; p < 8; ++p) {
      bool lt = key < top[p];
      u64 mn = lt ? key : top[p];
      key = lt ? top[p] : key;
      top[p] = mn;
    }
    top7f = inv_ordf((unsigned)(top[7] >> 32));
  }
}

// ---- prep: embedding fp32 -> bf16 (K-XOR-swizzled layout) + per-code ||e||^2 ----
__global__ void vq_prep(const float* __restrict__ emb, ushort* __restrict__ ebf,
                        float* __restrict__ esq) {
  int j = blockIdx.x, d = threadIdx.x;              // 1024 x 128
  float v = emb[j * KDIM + d];
  ebf[j * KDIM + (d ^ ((j & 7) << 3))] = f2bf(v);   // elem-XOR == byte ^ ((row&7)<<4)
  float s = v * v;
#pragma unroll
  for (int m = 1; m <= 32; m <<= 1) s += __shfl_xor(s, m);
  __shared__ float w[2];
  if ((threadIdx.x & 63) == 0) w[threadIdx.x >> 6] = s;
  __syncthreads();
  if (threadIdx.x == 0) esq[j] = w[0] + w[1];
}

// ---- main: swapped-operand dist GEMM + lane-local top8 + gather ----
__global__ __launch_bounds__(256, 4) void vq_main(
    const float* __restrict__ lat, const float* __restrict__ emb,
    const int* __restrict__ ksel, const ushort* __restrict__ ebf,
    const float* __restrict__ esq, float* __restrict__ out,
    float* __restrict__ partial) {
  __shared__ __align__(16) unsigned char smem[SMEM_SZ];
  ushort* fLds   = (ushort*)(smem);
  float*  esqLds = (float*)(smem + OFF_ESQ);
  float*  fsqLds = (float*)(smem + OFF_FSQ);
  int*    selLds = (int*)(smem + OFF_SEL);

  const int tid = threadIdx.x;
  const int lane = tid & 63, wid = tid >> 6;
  const int gR0 = blockIdx.x * BM;

  // prefetch code-chunk 0 -> ebuf0 (ebf is pre-swizzled; linear copy)
  {
    const char* src = (const char*)ebf + tid * 16;
    char* dst = (char*)smem + OFF_EBUF0 + tid * 16;
#pragma unroll
    for (int q = 0; q < 4; ++q) gload16(src + q * 4096, dst + q * 4096);
  }
  // all 1024 ||e||^2 -> LDS
  ((float4*)esqLds)[tid] = ((const float4*)esq)[tid];

  // stage latents (bf16) + per-row ||f||^2
#pragma unroll
  for (int it = 0; it < 8; ++it) {
    int i = tid + it * 256;
    int row = i >> 5, c4 = i & 31;
    float4 v = *(const float4*)(lat + (size_t)(gR0 + row) * KDIM + c4 * 4);
    float s = v.x * v.x + v.y * v.y + v.z * v.z + v.w * v.w;
#pragma unroll
    for (int m = 1; m <= 16; m <<= 1) s += __shfl_xor(s, m);
    if ((lane & 31) == 0) fsqLds[row] = s;
    ushort4 b; b.x = f2bf(v.x); b.y = f2bf(v.y); b.z = f2bf(v.z); b.w = f2bf(v.w);
    *(ushort4*)(&fLds[row * 136 + c4 * 4]) = b;
  }
  __syncthreads();

  const int n = lane & 15, hi = lane >> 4;
  // B-operand (latents) fragments -> registers, held for all chunks
  short8 bfr0, bfr1, bfr2, bfr3;
  {
    const ushort* fp = &fLds[(wid * 16 + n) * 136 + hi * 8];
    bfr0 = *(const short8*)(fp + 0);
    bfr1 = *(const short8*)(fp + 32);
    bfr2 = *(const short8*)(fp + 64);
    bfr3 = *(const short8*)(fp + 96);
  }
  // frag reads MUST complete before chunk-1 prefetch overwrites fLds region
  asm volatile("s_waitcnt lgkmcnt(0)" ::: "memory");

  u64 top[8];
#pragma unroll
  for (int p = 0; p < 8; ++p) top[p] = 0xFF800000FFFFFFFFull;  // +inf sentinel
  float top7f = __builtin_bit_cast(float, 0x7f800000u);

  const int xr = (n & 7) << 4;

#pragma unroll 2
  for (int nn = 0; nn < 16; ++nn) {
    const int cur = nn & 1;
    __builtin_amdgcn_s_barrier();            // ebuf[cur^1] reads done -> overwritable
    if (nn < 15) {
      const char* src = (const char*)ebf + (nn + 1) * 16384 + tid * 16;
      char* dst = (char*)smem + (cur ? OFF_EBUF0 : 0) + tid * 16;
#pragma unroll
      for (int q = 0; q < 4; ++q) gload16(src + q * 4096, dst + q * 4096);
      asm volatile("s_waitcnt vmcnt(4)" ::: "memory");   // my ebuf[cur] loads landed
    } else {
      asm volatile("s_waitcnt vmcnt(0)" ::: "memory");
    }
    __builtin_amdgcn_s_barrier();            // everyone's ebuf[cur] writes landed
    const char* eb = (const char*)smem + (cur ? 0 : OFF_EBUF0);

    f32x4 acc[4];
#pragma unroll
    for (int st = 0; st < 4; ++st) acc[st] = (f32x4){0.f, 0.f, 0.f, 0.f};

#pragma unroll
    for (int s = 0; s < 4; ++s) {
      short8 bb = (s == 0) ? bfr0 : (s == 1) ? bfr1 : (s == 2) ? bfr2 : bfr3;
      const int ko = (s * 32 + 16 * hi) ^ xr;
#pragma unroll
      for (int st = 0; st < 4; ++st) {
        short8 a = *(const short8*)(eb + (st * 16 + n) * 256 + ko);
        acc[st] = mfma16(a, bb, acc[st]);
      }
    }
    // score = ||e||^2 - 2*dot ; lane owns codes cb..cb+3 for its latent row
#pragma unroll
    for (int st = 0; st < 4; ++st) {
      const int cb = nn * 64 + st * 16 + 4 * hi;
      float4 eq = *(const float4*)(esqLds + cb);
      cand(eq.x - 2.f * acc[st][0], cb + 0, top, top7f);
      cand(eq.y - 2.f * acc[st][1], cb + 1, top, top7f);
      cand(eq.z - 2.f * acc[st][2], cb + 2, top, top7f);
      cand(eq.w - 2.f * acc[st][3], cb + 3, top, top7f);
    }
  }

  // dump per-lane sorted lists (transposed: conflict-light), merge 4 lists/row
  u64* mbuf = (u64*)((char*)smem + OFF_EBUF0);
#pragma unroll
  for (int p = 0; p < 8; ++p) mbuf[p * 256 + tid] = top[p];
  __syncthreads();

  if (tid < 64) {
    const int wr = tid >> 4, ln = tid & 15;
    const int b0 = wr * 64 + ln;
    int kk = ksel[tid & 7]; kk = kk < 0 ? 0 : (kk > 7 ? 7 : kk);
    u64 a0 = mbuf[b0], a1 = mbuf[b0 + 16], a2 = mbuf[b0 + 32], a3 = mbuf[b0 + 48];
    int i0 = 1, i1 = 1, i2 = 1, i3 = 1;
    u64 sel = a0;
    for (int s = 0; s <= kk; ++s) {
      u64 m01 = a0 < a1 ? a0 : a1;
      u64 m23 = a2 < a3 ? a2 : a3;
      sel = m01 < m23 ? m01 : m23;
      if (sel == a0)      { a0 = mbuf[i0 * 256 + b0];      ++i0; }
      else if (sel == a1) { a1 = mbuf[i1 * 256 + b0 + 16]; ++i1; }
      else if (sel == a2) { a2 = mbuf[i2 * 256 + b0 + 32]; ++i2; }
      else                { a3 = mbuf[i3 * 256 + b0 + 48]; ++i3; }
    }
    selLds[tid] = (int)(sel & 0xFFFFFFFFu);
    // row loss = score_sel + ||f||^2  (== ||q - f||^2)
    float rl = inv_ordf((unsigned)(sel >> 32)) + fsqLds[tid];
#pragma unroll
    for (int m = 1; m <= 32; m <<= 1) rl += __shfl_xor(rl, m);
    if (tid == 0) partial[blockIdx.x] = rl;
  }
  __syncthreads();

  // epilogue: gather selected fp32 code rows -> out (coalesced)
#pragma unroll
  for (int it = 0; it < 8; ++it) {
    int i = tid + it * 256;
    int row = i >> 5, c4 = i & 31;
    int s2 = selLds[row];
    float4 q = *(const float4*)(emb + (size_t)s2 * KDIM + c4 * 4);
    *(float4*)(out + (size_t)(gR0 + row) * KDIM + c4 * 4) = q;
  }
}

// ---- deterministic loss reduction over 1024 block partials ----
__global__ void vq_reduce(const float* __restrict__ p, float* __restrict__ loss) {
  int t = threadIdx.x;
  double s = (double)p[t] + (double)p[t + 256] + (double)p[t + 512] + (double)p[t + 768];
#pragma unroll
  for (int m = 1; m <= 32; m <<= 1) s += __shfl_xor(s, m);
  __shared__ double w[4];
  if ((t & 63) == 0) w[t >> 6] = s;
  __syncthreads();
  if (t == 0) loss[0] = (float)((w[0] + w[1] + w[2] + w[3]) * (1.25 / 8388608.0));
}

extern "C" void kernel_launch(void* const* d_in, const int* in_sizes, int n_in,
                              void* d_out, int out_size, void* d_ws, size_t ws_size,
                              hipStream_t stream) {
  const float* lat = (const float*)d_in[0];   // [8192,1024] fp32
  const float* emb = (const float*)d_in[1];   // [1024,128]  fp32
  const int* ksel = (const int*)d_in[2];      // [8] int32
  float* out = (float*)d_out;                 // quantized[8388608] + loss[1]

  ushort* ebf = (ushort*)d_ws;                          // 262144 B (swizzled bf16 codes)
  float* esq = (float*)((char*)d_ws + 262144);          // 4096 B
  float* partial = (float*)((char*)d_ws + 266240);      // 4096 B

  vq_prep<<<1024, 128, 0, stream>>>(emb, ebf, esq);
  vq_main<<<1024, 256, 0, stream>>>(lat, emb, ksel, ebf, esq, out, partial);
  vq_reduce<<<1, 256, 0, stream>>>(partial, out + NELEM);
}

// Round 3
// 44.489 us; speedup vs baseline: 5.2200x; 3.8395x over previous
//
#include <hip/hip_runtime.h>

#define KDIM   128
#define BM     64
#define NELEM  8388608

// LDS layout (bytes):
// [0,17408)      fLds ushort[64][136]  (ebuf1 aliases [0,16384) after setup)
// [17408,33792)  ebuf0 (16384)         (mbuf aliases it after the loop)
// [33792,37888)  esqmLds f32[1024]     (pre-scaled -0.5*||e||^2)
// [37888,38144)  fsqLds f32[64]
// [38144,38400)  selLds i32[64]
#define OFF_EBUF0 17408
#define OFF_ESQ   33792
#define OFF_FSQ   37888
#define OFF_SEL   38144
#define SMEM_SZ   38400

typedef __attribute__((ext_vector_type(8)))  short  short8;
typedef __attribute__((ext_vector_type(8)))  __bf16 bf16x8;
typedef __attribute__((ext_vector_type(4)))  float  f32x4;

__device__ inline ushort f2bf(float f) {            // RNE fp32 -> bf16
  unsigned u = __builtin_bit_cast(unsigned, f);
  u += 0x7fffu + ((u >> 16) & 1u);
  return (ushort)(u >> 16);
}
__device__ inline f32x4 mfma16(short8 a, short8 b, f32x4 c) {
  return __builtin_amdgcn_mfma_f32_16x16x32_bf16(
      __builtin_bit_cast(bf16x8, a), __builtin_bit_cast(bf16x8, b), c, 0, 0, 0);
}
__device__ inline void gload16(const void* g, void* l) {
  __builtin_amdgcn_global_load_lds(
      (const __attribute__((address_space(1))) unsigned*)g,
      (__attribute__((address_space(3))) unsigned*)l, 16, 0, 0);
}

// ---- prep: embedding fp32 -> bf16 (K-XOR-swizzled) + per-code -0.5*||e||^2 ----
__global__ void vq_prep(const float* __restrict__ emb, ushort* __restrict__ ebf,
                        float* __restrict__ esqm) {
  int j = blockIdx.x, d = threadIdx.x;              // 1024 x 128
  float v = emb[j * KDIM + d];
  ebf[j * KDIM + (d ^ ((j & 7) << 3))] = f2bf(v);   // elem-XOR == byte ^ ((row&7)<<4)
  float s = v * v;
#pragma unroll
  for (int m = 1; m <= 32; m <<= 1) s += __shfl_xor(s, m);
  __shared__ float w[2];
  if ((threadIdx.x & 63) == 0) w[threadIdx.x >> 6] = s;
  __syncthreads();
  if (threadIdx.x == 0) esqm[j] = -0.5f * (w[0] + w[1]);
}

// ---- main: swapped-operand GEMM, esq folded into acc-init, packed-key max-select ----
__global__ __launch_bounds__(256, 4) void vq_main(
    const float* __restrict__ lat, const float* __restrict__ emb,
    const int* __restrict__ ksel, const ushort* __restrict__ ebf,
    const float* __restrict__ esqm, float* __restrict__ out,
    float* __restrict__ partial) {
  __shared__ __align__(16) unsigned char smem[SMEM_SZ];
  ushort* fLds    = (ushort*)(smem);
  float*  esqmLds = (float*)(smem + OFF_ESQ);
  float*  fsqLds  = (float*)(smem + OFF_FSQ);
  int*    selLds  = (int*)(smem + OFF_SEL);

  const int tid = threadIdx.x;
  const int lane = tid & 63, wid = tid >> 6;
  const int gR0 = blockIdx.x * BM;

  // prefetch code-chunk 0 -> ebuf0 (ebf pre-swizzled; linear copy)
  {
    const char* src = (const char*)ebf + tid * 16;
    char* dst = (char*)smem + OFF_EBUF0 + tid * 16;
#pragma unroll
    for (int q = 0; q < 4; ++q) gload16(src + q * 4096, dst + q * 4096);
  }
  // all 1024 pre-scaled norms -> LDS
  ((float4*)esqmLds)[tid] = ((const float4*)esqm)[tid];

  // stage latents (bf16) + per-row ||f||^2
#pragma unroll
  for (int it = 0; it < 8; ++it) {
    int i = tid + it * 256;
    int row = i >> 5, c4 = i & 31;
    float4 v = *(const float4*)(lat + (size_t)(gR0 + row) * KDIM + c4 * 4);
    float s = v.x * v.x + v.y * v.y + v.z * v.z + v.w * v.w;
#pragma unroll
    for (int m = 1; m <= 16; m <<= 1) s += __shfl_xor(s, m);
    if ((lane & 31) == 0) fsqLds[row] = s;
    ushort4 b; b.x = f2bf(v.x); b.y = f2bf(v.y); b.z = f2bf(v.z); b.w = f2bf(v.w);
    *(ushort4*)(&fLds[row * 136 + c4 * 4]) = b;
  }
  __syncthreads();

  const int n = lane & 15, hi = lane >> 4;
  // B-operand (latents) fragments -> registers, held across all chunks
  short8 bfr[4];
  {
    const ushort* fp = &fLds[(wid * 16 + n) * 136 + hi * 8];
#pragma unroll
    for (int s = 0; s < 4; ++s) bfr[s] = *(const short8*)(fp + s * 32);
  }
  // frag reads MUST land before chunk-1 prefetch overwrites fLds region
  asm volatile("s_waitcnt lgkmcnt(0)" ::: "memory");

  // A-read bases: addr = n*256 + [(s*64+hi*16) ^ ((n&7)<<4)] + st*4096
  //             = base(s&1) + st*4096 + (s>>1)*128    (all imm after unroll)
  const int nm = n & 7;
  const int pb = ((hi ^ (nm & 3)) << 4) | (((nm >> 2) & 1) << 6);
  const char* aE0 = (const char*)smem + OFF_EBUF0 + n * 256 + pb;
  const char* aO0 = (const char*)smem + OFF_EBUF0 + n * 256 + (pb ^ 64);
  const char* aE1 = (const char*)smem + 0 + n * 256 + pb;
  const char* aO1 = (const char*)smem + 0 + n * 256 + (pb ^ 64);

  int cst[4][4];
#pragma unroll
  for (int st = 0; st < 4; ++st)
#pragma unroll
    for (int r = 0; r < 4; ++r) cst[st][r] = st * 16 + hi * 4 + r;

  float top[8];
#pragma unroll
  for (int p = 0; p < 8; ++p) top[p] = __builtin_bit_cast(float, 0xFF800000u); // -inf

#pragma unroll 2
  for (int nn = 0; nn < 16; ++nn) {
    __builtin_amdgcn_s_barrier();            // prev-buffer reads done -> overwritable
    if (nn < 15) {
      const char* src = (const char*)ebf + (nn + 1) * 16384 + tid * 16;
      char* dst = (char*)smem + ((nn & 1) ? OFF_EBUF0 : 0) + tid * 16;
#pragma unroll
      for (int q = 0; q < 4; ++q) gload16(src + q * 4096, dst + q * 4096);
      asm volatile("s_waitcnt vmcnt(4)" ::: "memory");   // my cur-chunk loads landed
    } else {
      asm volatile("s_waitcnt vmcnt(0)" ::: "memory");
    }
    __builtin_amdgcn_s_barrier();            // everyone's cur-chunk writes landed

    const char* aEb = (nn & 1) ? aE1 : aE0;
    const char* aOb = (nn & 1) ? aO1 : aO0;

    // acc init = -0.5*||e||^2  => acc_final = f.e - ||e||^2/2  (maximize)
    f32x4 acc[4];
    {
      const float* eq = esqmLds + nn * 64 + hi * 4;
#pragma unroll
      for (int st = 0; st < 4; ++st) acc[st] = *(const f32x4*)(eq + st * 16);
    }

#pragma unroll
    for (int s = 0; s < 4; ++s) {
      const char* ab = (s & 1) ? aOb : aEb;
      const int so = (s >> 1) * 128;
#pragma unroll
      for (int st = 0; st < 4; ++st) {
        short8 a = *(const short8*)(ab + st * 4096 + so);
        acc[st] = mfma16(a, bfr[s], acc[st]);
      }
    }

    // pack code into low-10 mantissa bits; per-32-code cell max; 2 sorted inserts
#pragma unroll
    for (int cell = 0; cell < 2; ++cell) {
      float k[8];
#pragma unroll
      for (int st = 0; st < 2; ++st)
#pragma unroll
        for (int r = 0; r < 4; ++r) {
          unsigned bb = (__builtin_bit_cast(unsigned, acc[cell * 2 + st][r]) & 0xFFFFFC00u)
                        | (unsigned)cst[cell * 2 + st][r];
          k[st * 4 + r] = __builtin_bit_cast(float, bb);
        }
      float x = fmaxf(fmaxf(k[0], k[1]), k[2]);
      float y = fmaxf(fmaxf(k[3], k[4]), k[5]);
      float z = fmaxf(k[6], k[7]);
      float c = fmaxf(fmaxf(x, y), z);
      unsigned cb = __builtin_bit_cast(unsigned, c) | (unsigned)(nn << 6);
      float key = __builtin_bit_cast(float, cb);
#pragma unroll
      for (int p = 0; p < 8; ++p) {        // descending top-8, branchless
        float mx = fmaxf(top[p], key);
        key = fminf(top[p], key);
        top[p] = mx;
      }
    }
  }

  // dump per-lane descending lists (transposed), merge 4 lists/row, pick k-th
  float* mbuf = (float*)(smem + OFF_EBUF0);
  __syncthreads();
#pragma unroll
  for (int p = 0; p < 8; ++p) mbuf[p * 256 + tid] = top[p];
  __syncthreads();

  if (tid < 64) {
    const int b0 = (tid >> 4) * 64 + (tid & 15);
    int kk = ksel[tid & 7]; kk = kk < 0 ? 0 : (kk > 7 ? 7 : kk);
    float a0 = mbuf[b0], a1 = mbuf[b0 + 16], a2 = mbuf[b0 + 32], a3 = mbuf[b0 + 48];
    int i0 = 1, i1 = 1, i2 = 1, i3 = 1;
    float sel = a0;
    for (int s = 0; s <= kk; ++s) {
      float m01 = fmaxf(a0, a1), m23 = fmaxf(a2, a3);
      sel = fmaxf(m01, m23);
      if (sel == a0)      { a0 = mbuf[i0 * 256 + b0];      ++i0; }
      else if (sel == a1) { a1 = mbuf[i1 * 256 + b0 + 16]; ++i1; }
      else if (sel == a2) { a2 = mbuf[i2 * 256 + b0 + 32]; ++i2; }
      else                { a3 = mbuf[i3 * 256 + b0 + 48]; ++i3; }
    }
    unsigned sb = __builtin_bit_cast(unsigned, sel);
    selLds[tid] = (int)(sb & 1023u);
    // row loss = ||f||^2 - 2*(f.e - ||e||^2/2) = ||q - f||^2
    float val = __builtin_bit_cast(float, sb & 0xFFFFFC00u);
    float rl = fsqLds[tid] - 2.0f * val;
#pragma unroll
    for (int m = 1; m <= 32; m <<= 1) rl += __shfl_xor(rl, m);
    if (tid == 0) partial[blockIdx.x] = rl;
  }
  __syncthreads();

  // epilogue: gather selected fp32 code rows -> out (coalesced)
#pragma unroll
  for (int it = 0; it < 8; ++it) {
    int i = tid + it * 256;
    int row = i >> 5, c4 = i & 31;
    int s2 = selLds[row];
    float4 q = *(const float4*)(emb + (size_t)s2 * KDIM + c4 * 4);
    *(float4*)(out + (size_t)(gR0 + row) * KDIM + c4 * 4) = q;
  }
}

// ---- deterministic loss reduction over 1024 block partials ----
__global__ void vq_reduce(const float* __restrict__ p, float* __restrict__ loss) {
  int t = threadIdx.x;
  double s = (double)p[t] + (double)p[t + 256] + (double)p[t + 512] + (double)p[t + 768];
#pragma unroll
  for (int m = 1; m <= 32; m <<= 1) s += __shfl_xor(s, m);
  __shared__ double w[4];
  if ((t & 63) == 0) w[t >> 6] = s;
  __syncthreads();
  if (t == 0) loss[0] = (float)((w[0] + w[1] + w[2] + w[3]) * (1.25 / 8388608.0));
}

extern "C" void kernel_launch(void* const* d_in, const int* in_sizes, int n_in,
                              void* d_out, int out_size, void* d_ws, size_t ws_size,
                              hipStream_t stream) {
  const float* lat = (const float*)d_in[0];   // [8192,1024] fp32
  const float* emb = (const float*)d_in[1];   // [1024,128]  fp32
  const int* ksel = (const int*)d_in[2];      // [8] int32
  float* out = (float*)d_out;                 // quantized[8388608] + loss[1]

  ushort* ebf = (ushort*)d_ws;                          // 262144 B (swizzled bf16 codes)
  float* esqm = (float*)((char*)d_ws + 262144);         // 4096 B (-0.5*||e||^2)
  float* partial = (float*)((char*)d_ws + 266240);      // 4096 B

  vq_prep<<<1024, 128, 0, stream>>>(emb, ebf, esqm);
  vq_main<<<1024, 256, 0, stream>>>(lat, emb, ksel, ebf, esqm, out, partial);
  vq_reduce<<<1, 256, 0, stream>>>(partial, out + NELEM);
}